// Round 4
// baseline (139.997 us; speedup 1.0000x reference)
//
#include <hip/hip_runtime.h>
#include <math.h>

// RGate on 22 qubits: y = (⊗_i exp(-0.5i*angle[i]*sigma_x)) x
//   x:     float32[2^22]  (d_in[0])
//   angle: float32[22]    (d_in[1])
//   out:   float32[2^22]  (d_out) = REAL part of final complex state.
// Site n acts on global bit b = 21-n; gate on bit b uses angle[21-b].
// Butterfly (M = [[c,-is],[-is,c]], symmetric):
//   a' = (c*ar + s*bi, c*ai - s*br);  b' = (c*br + s*ai, c*bi - s*ar)
// Side-symmetric cross-lane form (same formula both sides, p = partner):
//   v' = (c*v.x + s*p.y, c*v.y - s*p.x)
//
// R3: ATTRIBUTION PROBE. Kernels are byte-identical to R2; kernel_launch runs
// the (pass1, pass2) pair THREE times. Legal because the pair is idempotent:
// pass1 fully recomputes mid from x (x never written), pass2 fully transforms
// d_out; final output bit-identical. With dur(R2) = tax + C and
// dur(R3) = tax + 3C, the true pass-pair cost is C = (dur_R3 - 87.4)/2.
// Pipe model predicts C ~= 10-14 us (dur ~= 107-115); if C >= 30 the passes
// are the real target and we attack with occupancy/fusion next.
//
// Pass 1: bits 0..12 (angles 21..9), x -> packed-bf16 complex mid (in d_out).
// Pass 2: bits 13..21 (angles 8..0), mid -> f32 real parts, in place in d_out.
// d_ws unused (R0: 256-MiB poison fill is timed unconditionally regardless).

static __device__ __forceinline__ float bf2f(unsigned short u) {
    return __uint_as_float(((unsigned int)u) << 16);
}
static __device__ __forceinline__ unsigned short f2bf(float f) {
    unsigned int x = __float_as_uint(f);
    x += 0x7FFFu + ((x >> 16) & 1u);          // round-to-nearest-even
    return (unsigned short)(x >> 16);
}
static __device__ __forceinline__ unsigned int packc(float2 v) {
    return (unsigned int)f2bf(v.x) | ((unsigned int)f2bf(v.y) << 16);
}
static __device__ __forceinline__ float2 unpackc(unsigned int u) {
    return make_float2(bf2f((unsigned short)(u & 0xFFFFu)),
                       bf2f((unsigned short)(u >> 16)));
}

static __device__ __forceinline__ void bfly(float2& a, float2& b, float c, float s) {
    float ar = a.x, ai = a.y, br = b.x, bi = b.y;
    a.x = fmaf(c, ar,  s * bi);
    a.y = fmaf(c, ai, -s * br);
    b.x = fmaf(c, br,  s * ai);
    b.y = fmaf(c, bi, -s * ar);
}

// LDS swizzle at float4 granularity (preserves float2-pair adjacency for b128):
// float4 slot f -> f ^ ((f>>3)&7). All b64/b128 phases below are at the
// structural bank floor (enumerated per-round in comments).
static __device__ __forceinline__ unsigned swf(unsigned f) {
    return f ^ ((f >> 3) & 7u);
}
// float2-unit address e -> swizzled float2 address.
static __device__ __forceinline__ unsigned swe(unsigned e) {
    return (swf(e >> 1) << 1) | (e & 1u);
}

// ---------------- Pass 1: global bits 0..12 (angles 21..9) ----------------
// 512 blocks x 512 threads; tile = 8192 contiguous complex (64 KB LDS f32).
// Phases: A = bits 0..3 (from global, b128 LDS store), barrier, B = bits 4..7
// (b64 LDS rw), barrier, C = bits 11..12 (k pairs) + 8..10 (shfl_xor 1/2/4)
// + bf16 pack + DIRECT uint4 global store. 3 barriers total (incl. csb init).
__global__ __launch_bounds__(512) void rgate_pass1(
    const float* __restrict__ x, const float* __restrict__ ang,
    unsigned int* __restrict__ mid)
{
    __shared__ __align__(16) float2 tile[8192];
    __shared__ float2 csb[13];                    // csb[j] = (cos,sin)(angle[9+j]/2)
    float4* t4 = (float4*)tile;
    const unsigned t = threadIdx.x;
    if (t < 13) {
        float s, c; sincosf(0.5f * ang[9 + t], &s, &c);
        csb[t] = make_float2(c, s);
    }
    __syncthreads();

    const unsigned base = (unsigned)blockIdx.x << 13;
    float2 v[16];

    // Round A: thread owns 16 CONSECUTIVE elements e = t*16+k -> 4 float4 loads
    // (64 B/lane, wave reads 4 KB contiguous). Gates bits 0..3 = csb[12-j].
    {
        const float4* x4 = (const float4*)(x + base);
        #pragma unroll
        for (int q = 0; q < 4; ++q) {
            const float4 f = x4[(t << 2) + (unsigned)q];
            v[4*q+0] = make_float2(f.x, 0.0f);
            v[4*q+1] = make_float2(f.y, 0.0f);
            v[4*q+2] = make_float2(f.z, 0.0f);
            v[4*q+3] = make_float2(f.w, 0.0f);
        }
    }
    #pragma unroll
    for (int j = 0; j < 4; ++j) {
        const float2 g = csb[12 - j];
        const int m = 1 << j;
        #pragma unroll
        for (int k = 0; k < 16; ++k)
            if (!(k & m)) bfly(v[k], v[k | m], g.x, g.y);
    }
    // b128 stores, slots f = t*8+q; swf spreads q across bank groups (floor).
    #pragma unroll
    for (int q = 0; q < 8; ++q) {
        const unsigned f = (t << 3) + (unsigned)q;
        t4[swf(f)] = make_float4(v[2*q].x, v[2*q].y, v[2*q+1].x, v[2*q+1].y);
    }
    __syncthreads();

    // Round B: e = lo + k*16 + hi*256 (lo = t&15 -> bits 0..3, k -> 4..7,
    // hi = t>>4 in 0..31 -> bits 8..12). Gates bits 4..7 = csb[8-j].
    {
        const unsigned lo = t & 15u, hi = t >> 4;
        #pragma unroll
        for (int k = 0; k < 16; ++k)
            v[k] = tile[swe(lo + ((unsigned)k << 4) + (hi << 8))];
        #pragma unroll
        for (int j = 0; j < 4; ++j) {
            const float2 g = csb[8 - j];
            const int m = 1 << j;
            #pragma unroll
            for (int k = 0; k < 16; ++k)
                if (!(k & m)) bfly(v[k], v[k | m], g.x, g.y);
        }
        #pragma unroll
        for (int k = 0; k < 16; ++k)
            tile[swe(lo + ((unsigned)k << 4) + (hi << 8))] = v[k];
    }
    __syncthreads();

    // Round C: e = (k&3) | (t>>3)<<2 | (t&7)<<8 | (k>>2)<<11 (bijective:
    // e{0..1}<-k{0..1}, e{2..7}<-t{3..8}, e{8..10}<-t{0..2}=LANE{0..2},
    // e{11..12}<-k{2..3}). Read 2xb128 per k-group (4 consecutive e).
    {
        const unsigned cb = ((t >> 3) << 1) | ((t & 7u) << 7);   // f-base
        #pragma unroll
        for (int g = 0; g < 4; ++g) {
            const unsigned f0 = cb | ((unsigned)g << 10);
            const float4 r0 = t4[swf(f0)];
            const float4 r1 = t4[swf(f0 | 1u)];
            v[4*g+0] = make_float2(r0.x, r0.y);
            v[4*g+1] = make_float2(r0.z, r0.w);
            v[4*g+2] = make_float2(r1.x, r1.y);
            v[4*g+3] = make_float2(r1.z, r1.w);
        }
    }
    // Gates bits 11 (csb[1], m=4) and 12 (csb[0], m=8): register pairs.
    {
        const float2 g1 = csb[1];
        #pragma unroll
        for (int k = 0; k < 16; ++k)
            if (!(k & 4)) bfly(v[k], v[k | 4], g1.x, g1.y);
        const float2 g0 = csb[0];
        #pragma unroll
        for (int k = 0; k < 16; ++k)
            if (!(k & 8)) bfly(v[k], v[k | 8], g0.x, g0.y);
    }
    // Gates bits 8,9,10 = csb[4],csb[3],csb[2] via shfl_xor(1/2/4): partner's
    // (re,im) pulled cross-lane; side-symmetric form, no divergence.
    {
        const float2 ga = csb[4];
        #pragma unroll
        for (int k = 0; k < 16; ++k) {
            const float px = __shfl_xor(v[k].x, 1);
            const float py = __shfl_xor(v[k].y, 1);
            v[k] = make_float2(fmaf(ga.x, v[k].x,  ga.y * py),
                               fmaf(ga.x, v[k].y, -ga.y * px));
        }
        const float2 gb = csb[3];
        #pragma unroll
        for (int k = 0; k < 16; ++k) {
            const float px = __shfl_xor(v[k].x, 2);
            const float py = __shfl_xor(v[k].y, 2);
            v[k] = make_float2(fmaf(gb.x, v[k].x,  gb.y * py),
                               fmaf(gb.x, v[k].y, -gb.y * px));
        }
        const float2 gc = csb[2];
        #pragma unroll
        for (int k = 0; k < 16; ++k) {
            const float px = __shfl_xor(v[k].x, 4);
            const float py = __shfl_xor(v[k].y, 4);
            v[k] = make_float2(fmaf(gc.x, v[k].x,  gc.y * py),
                               fmaf(gc.x, v[k].y, -gc.y * px));
        }
    }
    // Pack each 4-element k-group to one uint4, store direct to global.
    {
        uint4* m4 = (uint4*)(mid + base);
        const unsigned ob = (t >> 3) | ((t & 7u) << 6);
        #pragma unroll
        for (int g = 0; g < 4; ++g) {
            uint4 u;
            u.x = packc(v[4*g+0]);
            u.y = packc(v[4*g+1]);
            u.z = packc(v[4*g+2]);
            u.w = packc(v[4*g+3]);
            m4[ob | ((unsigned)g << 9)] = u;
        }
    }
}

// ---------------- Pass 2: global bits 13..21 (angles 8..0) ----------------
// 512 blocks x 512 threads. l = bits 0..3 (16 contiguous complex = 64-B
// granule), h = bits 13..21 (512 values); blk covers bits 4..12. Tile = 8192
// complex (64 KB f32), logical e = h*16 + l, stored at swe(e).
// Global element g = (h<<13)|(blk<<4)|l. XCD remap: 64 consecutive logical
// blks per XCD so adjacent 64-B granules share 128-B L2 lines.
// IN-PLACE in d_out: block's read bytes == write bytes; reads drain at the
// first barrier before any write; byte sets partitioned by blk across blocks.
__global__ __launch_bounds__(512) void rgate_pass2(
    const unsigned int* mid, const float* __restrict__ ang,
    float* outr)   // same buffer as mid (d_out), different interpretation
{
    __shared__ __align__(16) float2 tile[8192];
    __shared__ float2 csb[9];                     // csb[j] = (cos,sin)(angle[j]/2)
    float4* t4 = (float4*)tile;
    const unsigned t = threadIdx.x;
    if (t < 9) {
        float s, c; sincosf(0.5f * ang[t], &s, &c);
        csb[t] = make_float2(c, s);
    }
    __syncthreads();

    const unsigned p = blockIdx.x;
    const unsigned blk = ((p & 7u) << 6) | (p >> 3);   // XCD-grouped logical blk
    const uint2* g2 = (const uint2*)mid;               // 1 uint2 = 2 packed complex
    float2 v[16];
    const unsigned tl = t & 7u;                        // l-pair index (l = 2*tl)
    const unsigned th = t >> 3;                        // h bits 3..8

    // Round A: k covers h bits 0..2 (global 13..15, angles 8..6 = csb[8-j]).
    {
        #pragma unroll
        for (int k = 0; k < 8; ++k) {
            const unsigned h = (th << 3) | (unsigned)k;
            const uint2 u = g2[(h << 12) + (blk << 3) + tl];
            v[2*k]   = unpackc(u.x);
            v[2*k+1] = unpackc(u.y);
        }
        #pragma unroll
        for (int j = 0; j < 3; ++j) {
            const float2 g = csb[8 - j];
            const int m = 2 << j;                      // v-index bits 1..3 = h bits 0..2
            #pragma unroll
            for (int k = 0; k < 16; ++k)
                if (!(k & m)) bfly(v[k], v[k | m], g.x, g.y);
        }
        #pragma unroll
        for (int k = 0; k < 8; ++k) {
            const unsigned h = (th << 3) | (unsigned)k;
            const unsigned f = (h << 3) + tl;          // float4 slot of e=(h<<4)+2*tl
            t4[swf(f)] = make_float4(v[2*k].x, v[2*k].y, v[2*k+1].x, v[2*k+1].y);
        }
    }
    __syncthreads();   // also drains all round-A global reads (in-place safety)

    // Round B: k covers h bits 3..6 (global 16..19, angles 5..2 = csb[5-j]).
    {
        const unsigned abase = (t & 127u) + ((t >> 7) << 11);
        #pragma unroll
        for (int k = 0; k < 16; ++k)
            v[k] = tile[swe(abase + ((unsigned)k << 7))];
        #pragma unroll
        for (int j = 0; j < 4; ++j) {
            const float2 g = csb[5 - j];
            const int m = 1 << j;
            #pragma unroll
            for (int k = 0; k < 16; ++k)
                if (!(k & m)) bfly(v[k], v[k | m], g.x, g.y);
        }
        #pragma unroll
        for (int k = 0; k < 16; ++k)
            tile[swe(abase + ((unsigned)k << 7))] = v[k];
    }
    __syncthreads();

    // Round C: e = t + k*512. Gates e bits 11..12 (global 20..21, angles 1..0).
    {
        #pragma unroll
        for (int k = 0; k < 16; ++k)
            v[k] = tile[swe(t + ((unsigned)k << 9))];
        {
            const float2 g1 = csb[1];
            #pragma unroll
            for (int k = 0; k < 16; ++k)
                if (!(k & 4)) bfly(v[k], v[k | 4], g1.x, g1.y);
            const float2 g0 = csb[0];
            #pragma unroll
            for (int k = 0; k < 16; ++k)
                if (!(k & 8)) bfly(v[k], v[k | 8], g0.x, g0.y);
        }
        // f32 REAL parts: 64-B write granules, same bytes as round-A reads.
        #pragma unroll
        for (int k = 0; k < 16; ++k) {
            const unsigned e = t + ((unsigned)k << 9);
            outr[((e >> 4) << 13) + (blk << 4) + (e & 15u)] = v[k].x;
        }
    }
}

extern "C" void kernel_launch(void* const* d_in, const int* in_sizes, int n_in,
                              void* d_out, int out_size, void* d_ws, size_t ws_size,
                              hipStream_t stream) {
    (void)in_sizes; (void)n_in; (void)out_size; (void)d_ws; (void)ws_size;
    const float* x   = (const float*)d_in[0];   // float32[2^22]
    const float* ang = (const float*)d_in[1];   // float32[22]

    unsigned int* mid = (unsigned int*)d_out;
    float* outr = (float*)d_out;

    // R3 attribution probe: run the idempotent pair 3x. Output bit-identical
    // (pass1 recomputes mid from untouched x each time). dur(R3)-dur(R2) = 2C
    // where C = true cost of one (pass1+pass2) pair, invisible in top-5.
    #pragma unroll
    for (int rep = 0; rep < 3; ++rep) {
        rgate_pass1<<<512, 512, 0, stream>>>(x, ang, mid);
        rgate_pass2<<<512, 512, 0, stream>>>(mid, ang, outr);
    }
}

// Round 5
// 97.548 us; speedup vs baseline: 1.4352x; 1.4352x over previous
//
#include <hip/hip_runtime.h>
#include <math.h>

// RGate on 22 qubits, REAL-spectral form (R4 rewrite).
//   x: float32[2^22] (d_in[0]); angle: float32[22] (d_in[1]); out = Re(U x).
// All gates commute: exp(-i*th/2*sx) = H diag(e^{-i th/2}, e^{+i th/2}) H.
// => U = (xH) D (xH), and with x, H real:
//   y = WHT( g .* WHT(x) ) ,  g_b = cos(phi_b) * 2^-22,
//   phi_b = T/2 - sum_{beta: b_beta=1} theta_beta,  theta_beta = angle[21-beta],
//   T = sum(angle).  (cos is even -> sign convention of phi irrelevant.)
// WHT = unnormalized Walsh-Hadamard butterflies: (a,b) -> (a+b, a-b).
// Verified 1-qubit: y = (c x0, c x1) = W(c/2 .* Wx). 2^-22 folded into g once.
//
// R3 probe: pair cost C = (140.0-87.4)/2 = 26.3 us vs ~61 us untouchable
// harness tax (256-MiB d_ws fill etc). C is VALU/LDS-bound (complex bfly =
// 8 VALU/pair). This rewrite: real bfly = 2 VALU/pair (4x less VALU), no
// bf16 pack/unpack, half the LDS/register bytes. 3 passes:
//   P1: WHT bits 0..12  (contiguous 8192-f32 tile, 32 KB LDS)
//   P2: WHT bits 13..21, then g, then WHT bits 13..21 again (tile over
//       bits {0..3 (l-granule), 13..21 (h)}; D needs all forward gates done:
//       bits 0..12 from P1, 13..21 in-tile -> legal)
//   P3: WHT bits 0..12 again (same kernel as P1, in-place)
// All passes 512 blocks x 512 threads, 16 f32/thread, 2 barriers each.
// In-place safety: each block's global read set == write set; reads drain at
// the first __syncthreads (vmcnt(0)) before any global write. d_ws unused.
//
// Numerics: pure f32; butterfly (pairwise) summation; values peak ~2e4 at the
// D step (sd 2^11), final O(1). cos via sincosf (args <~140 rad, f32-exact
// enough: err ~1e-5 << 0.0156 tol). Expect absmax <= 0.015625.

// ---- LDS swizzles (bank floor enumerated per phase in comments) ----
// P1 slot swizzle (float4-quad preserving): swp(f) = f ^ ((f>>4)&7).
//   A-store f=(t<<2)|q: group f'&7 = (q0^t2, q1^t3, t0^t4) -> 8 lanes/group (floor).
//   B r/w  e=lo|k<<4|hi<<8 (b32): bank = [lo0,lo1,lo2^k2,lo3^k3,k0^t4]:
//     fixed k: t0..4 -> 32 banks, t5 dup -> 2-way (free, m136).
//   C-read f=(t>>3)|((t&7)<<6)|(g<<9): group = (t3^t7, t4^t8, t5^t0) -> 8/group.
static __device__ __forceinline__ unsigned swp(unsigned f) {
    return f ^ ((f >> 4) & 7u);
}
static __device__ __forceinline__ unsigned sw1(unsigned e) {
    return (swp(e >> 2) << 2) | (e & 3u);
}
// P2 element swizzle (b32-only phases, no quads): e'1..4 ^= e5..8.
//   A-write e=(hu<<8)|(k<<4)|l: bank = [l0, l1^k1, l2^k2, l3^k3, k0^t4]:
//     fixed k: t0..3(l)+t4 -> 32 banks, t5 dup -> 2-way free.
//   B r/w  e=eb|k<<9 (e0..3=t5..8, e4..7=t0..3, e8=t4): bank =
//     [t5, l1^t1, l2^t2, l3^t3, t0^t4]: 32 banks, (t0,t4)-kernel 2-way free.
static __device__ __forceinline__ unsigned sw2(unsigned e) {
    return e ^ (((e >> 5) & 15u) << 1);
}

// ---------------- P1/P3: WHT on bits 0..12 (contiguous tile) ----------------
// Phases: A: 4 float4 loads (e=t*16+k), gates bits 0..3 on k, b128 LDS store.
//         B: b32 r/w, e = lo + k*16 + hi*256, gates bits 4..7 on k.
//         C: b128 reads, e = k01 | (t>>3)<<2 | (t&7)<<8 | k23<<11:
//            gates bit 11 (k^4), bit 12 (k^8), bits 8,9,10 via shfl_xor(1,2,4)
//            [WHT lane form: v' = s*v + p, s = (lane&m)? -1:+1], float4 store.
// No angles needed (WHT is add/sub only). No __restrict__: P3 runs in-place.
__global__ __launch_bounds__(512) void rgate_wht13(const float* in, float* out)
{
    __shared__ __align__(16) float tile[8192];
    float4* t4 = (float4*)tile;
    const unsigned t = threadIdx.x;
    const unsigned base = (unsigned)blockIdx.x << 13;
    float v[16];

    // Phase A
    {
        const float4* x4 = (const float4*)(in + base);
        #pragma unroll
        for (int q = 0; q < 4; ++q) {
            const float4 f = x4[(t << 2) + (unsigned)q];
            v[4*q+0] = f.x; v[4*q+1] = f.y; v[4*q+2] = f.z; v[4*q+3] = f.w;
        }
    }
    #pragma unroll
    for (int j = 0; j < 4; ++j) {                  // bits 0..3
        const int m = 1 << j;
        #pragma unroll
        for (int k = 0; k < 16; ++k)
            if (!(k & m)) { const float a = v[k], b = v[k|m]; v[k] = a + b; v[k|m] = a - b; }
    }
    #pragma unroll
    for (int q = 0; q < 4; ++q)
        t4[swp((t << 2) | (unsigned)q)] = make_float4(v[4*q], v[4*q+1], v[4*q+2], v[4*q+3]);
    __syncthreads();

    // Phase B
    {
        const unsigned lo = t & 15u, hi = t >> 4;
        #pragma unroll
        for (int k = 0; k < 16; ++k)
            v[k] = tile[sw1(lo | ((unsigned)k << 4) | (hi << 8))];
        #pragma unroll
        for (int j = 0; j < 4; ++j) {              // bits 4..7
            const int m = 1 << j;
            #pragma unroll
            for (int k = 0; k < 16; ++k)
                if (!(k & m)) { const float a = v[k], b = v[k|m]; v[k] = a + b; v[k|m] = a - b; }
        }
        #pragma unroll
        for (int k = 0; k < 16; ++k)
            tile[sw1(lo | ((unsigned)k << 4) | (hi << 8))] = v[k];
    }
    __syncthreads();

    // Phase C
    {
        const unsigned fb = (t >> 3) | ((t & 7u) << 6);
        #pragma unroll
        for (int g = 0; g < 4; ++g) {
            const float4 r = t4[swp(fb | ((unsigned)g << 9))];
            v[4*g+0] = r.x; v[4*g+1] = r.y; v[4*g+2] = r.z; v[4*g+3] = r.w;
        }
        #pragma unroll
        for (int k = 0; k < 16; ++k)               // bit 11 (e11 = k2)
            if (!(k & 4)) { const float a = v[k], b = v[k|4]; v[k] = a + b; v[k|4] = a - b; }
        #pragma unroll
        for (int k = 0; k < 16; ++k)               // bit 12 (e12 = k3)
            if (!(k & 8)) { const float a = v[k], b = v[k|8]; v[k] = a + b; v[k|8] = a - b; }
        const float s1 = (t & 1u) ? -1.f : 1.f;    // bits 8,9,10 on lanes 0..2
        const float s2 = (t & 2u) ? -1.f : 1.f;
        const float s4 = (t & 4u) ? -1.f : 1.f;
        #pragma unroll
        for (int k = 0; k < 16; ++k) { const float p = __shfl_xor(v[k], 1); v[k] = fmaf(s1, v[k], p); }
        #pragma unroll
        for (int k = 0; k < 16; ++k) { const float p = __shfl_xor(v[k], 2); v[k] = fmaf(s2, v[k], p); }
        #pragma unroll
        for (int k = 0; k < 16; ++k) { const float p = __shfl_xor(v[k], 4); v[k] = fmaf(s4, v[k], p); }
        // Store: per (wave, g): 8 clusters of 8 consecutive float4 = 8 full
        // 128-B lines; all lines fully written.
        float4* o4 = (float4*)(out + base);
        #pragma unroll
        for (int g = 0; g < 4; ++g)
            o4[fb | ((unsigned)g << 9)] = make_float4(v[4*g], v[4*g+1], v[4*g+2], v[4*g+3]);
    }
}

// ---------------- P2: WHT bits 13..21, ⊙ g, WHT bits 13..21 ----------------
// Tile e = (h<<4)|l: l = b0..3 (16 contiguous f32 = 64-B granules), h = b13..21.
// blk = b4..12 (XCD-grouped). Global f32 index = (h<<13)|(blk<<4)|l.
// Phase A:  read; gates h0..3 (b13..16) on k; sw2 LDS write.
// Phase B:  read (k = h5..8); shfl gate b17 (lane 16); k-gates b18..21;
//           D: v *= 2^-22*cos(phi) via per-thread sincosf + csk[k] table;
//           k-gates b18..21 again; shfl b17 again; write back.
// Phase A': read; gates b13..16 again; store global (same bytes as A read).
// In-place: reads drained at first barrier; block read set == write set.
__global__ __launch_bounds__(512) void rgate_whtmid(float* buf, const float* __restrict__ ang)
{
    __shared__ float tile[8192];
    __shared__ float2 csk[16];    // (cos,sin) of S_k over b18..21 (angle[3-j])
    __shared__ float tha[22];
    const unsigned t = threadIdx.x;
    if (t < 22) tha[t] = ang[t];
    if (t < 16) {
        float S = 0.f;
        if (t & 1u) S += ang[3];
        if (t & 2u) S += ang[2];
        if (t & 4u) S += ang[1];
        if (t & 8u) S += ang[0];
        float sn, cs; sincosf(S, &sn, &cs);
        csk[t] = make_float2(cs, sn);
    }
    const unsigned p = blockIdx.x;
    const unsigned blk = ((p & 7u) << 6) | (p >> 3);   // XCD-grouped logical blk
    float v[16];
    const unsigned tl = t & 15u;                       // l
    const unsigned hu = t >> 4;                        // h4..8

    // Phase A: h = (hu<<4)|k; 16 lanes x 4 B = 64-B read granules.
    #pragma unroll
    for (int k = 0; k < 16; ++k)
        v[k] = buf[(((hu << 4) | (unsigned)k) << 13) + (blk << 4) + tl];
    #pragma unroll
    for (int j = 0; j < 4; ++j) {                      // b13..16
        const int m = 1 << j;
        #pragma unroll
        for (int k = 0; k < 16; ++k)
            if (!(k & m)) { const float a = v[k], b = v[k|m]; v[k] = a + b; v[k|m] = a - b; }
    }
    #pragma unroll
    for (int k = 0; k < 16; ++k)
        tile[sw2((hu << 8) | ((unsigned)k << 4) | tl)] = v[k];
    __syncthreads();   // drains all phase-A global reads (in-place safety)

    // Phase B: e0..3 = t5..8 (l), e4..7 = t0..3 (h0..3), e8 = t4 (h4), k = h5..8.
    const unsigned eb = (t >> 5) | ((t & 15u) << 4) | (((t >> 4) & 1u) << 8);
    #pragma unroll
    for (int k = 0; k < 16; ++k)
        v[k] = tile[sw2(eb | ((unsigned)k << 9))];
    const float s17 = (t & 16u) ? -1.f : 1.f;          // b17 on lane bit 4
    #pragma unroll
    for (int k = 0; k < 16; ++k) { const float pp = __shfl_xor(v[k], 16); v[k] = fmaf(s17, v[k], pp); }
    #pragma unroll
    for (int j = 0; j < 4; ++j) {                      // b18..21
        const int m = 1 << j;
        #pragma unroll
        for (int k = 0; k < 16; ++k)
            if (!(k & m)) { const float a = v[k], b = v[k|m]; v[k] = a + b; v[k|m] = a - b; }
    }
    // D: g = 2^-22 * cos(phi_f - S_k) = cf*cos(S_k) + sf*sin(S_k).
    {
        float T = 0.f;
        #pragma unroll
        for (int i = 0; i < 22; ++i) T += tha[i];      // broadcast LDS reads
        float S = 0.f;                                 // thread-fixed set bits
        if (t & 1u)   S += tha[8];                     // h0 = b13
        if (t & 2u)   S += tha[7];
        if (t & 4u)   S += tha[6];
        if (t & 8u)   S += tha[5];                     // h3 = b16
        if (t & 16u)  S += tha[4];                     // h4 = b17
        if (t & 32u)  S += tha[21];                    // l0 = b0
        if (t & 64u)  S += tha[20];
        if (t & 128u) S += tha[19];
        if (t & 256u) S += tha[18];                    // l3 = b3
        #pragma unroll
        for (int j = 0; j < 9; ++j)                    // blk bit j = b(4+j)
            if (blk & (1u << j)) S += tha[17 - j];
        float sp, cp; sincosf(0.5f * T - S, &sp, &cp);
        const float cf = cp * (1.f / 4194304.f);       // fold 2^-22 here (once)
        const float sf = sp * (1.f / 4194304.f);
        #pragma unroll
        for (int k = 0; k < 16; ++k)
            v[k] *= fmaf(cf, csk[k].x, sf * csk[k].y);
    }
    // Second WHT application, same gates (order free, all commute).
    #pragma unroll
    for (int j = 0; j < 4; ++j) {                      // b18..21
        const int m = 1 << j;
        #pragma unroll
        for (int k = 0; k < 16; ++k)
            if (!(k & m)) { const float a = v[k], b = v[k|m]; v[k] = a + b; v[k|m] = a - b; }
    }
    #pragma unroll
    for (int k = 0; k < 16; ++k) { const float pp = __shfl_xor(v[k], 16); v[k] = fmaf(s17, v[k], pp); }
    #pragma unroll
    for (int k = 0; k < 16; ++k)
        tile[sw2(eb | ((unsigned)k << 9))] = v[k];
    __syncthreads();

    // Phase A': b13..16 again, store to the same global bytes phase A read.
    #pragma unroll
    for (int k = 0; k < 16; ++k)
        v[k] = tile[sw2((hu << 8) | ((unsigned)k << 4) | tl)];
    #pragma unroll
    for (int j = 0; j < 4; ++j) {
        const int m = 1 << j;
        #pragma unroll
        for (int k = 0; k < 16; ++k)
            if (!(k & m)) { const float a = v[k], b = v[k|m]; v[k] = a + b; v[k|m] = a - b; }
    }
    #pragma unroll
    for (int k = 0; k < 16; ++k)
        buf[(((hu << 4) | (unsigned)k) << 13) + (blk << 4) + tl] = v[k];
}

extern "C" void kernel_launch(void* const* d_in, const int* in_sizes, int n_in,
                              void* d_out, int out_size, void* d_ws, size_t ws_size,
                              hipStream_t stream) {
    (void)in_sizes; (void)n_in; (void)out_size; (void)d_ws; (void)ws_size;
    const float* x   = (const float*)d_in[0];   // float32[2^22]
    const float* ang = (const float*)d_in[1];   // float32[22]
    float* out = (float*)d_out;

    // y = WHT( g .* WHT(x) ) / (folded 2^-22 in P2's D step):
    rgate_wht13 <<<512, 512, 0, stream>>>(x, out);     // P1: bits 0..12
    rgate_whtmid<<<512, 512, 0, stream>>>(out, ang);   // P2: bits 13..21 + D + bits 13..21
    rgate_wht13 <<<512, 512, 0, stream>>>(out, out);   // P3: bits 0..12 (in-place)
}

// Round 6
// 91.832 us; speedup vs baseline: 1.5245x; 1.0622x over previous
//
#include <hip/hip_runtime.h>
#include <math.h>

// RGate on 22 qubits: y = (⊗_i exp(-0.5i*angle[i]*sigma_x)) x
//   x:     float32[2^22]  (d_in[0])
//   angle: float32[22]    (d_in[1])
//   out:   float32[2^22]  (d_out) = REAL part of final complex state.
// Site n acts on global bit b = 21-n; gate on bit b uses angle[21-b].
// Butterfly (M = [[c,-is],[-is,c]], symmetric):
//   a' = (c*ar + s*bi, c*ai - s*br);  b' = (c*br + s*ai, c*bi - s*ar)
// Side-symmetric cross-lane form (same formula both sides, p = partner):
//   v' = (c*v.x + s*p.y, c*v.y - s*p.x)
//
// R5: back to the verified R2 complex 2-pass structure (minimum 64 MB traffic;
// R4 proved VALU is not the limiter), with ONE change: mid layout permuted to
//   m = (lo>>4)<<13 | H<<4 | (lo&15)   (lo = bits 0..12, H = bits 13..21)
// so that P2's strided 64-B GATHER (the ~13 us pig: latency-exposed reads at
// 32-KB stride) becomes P1's strided WRITE (cheap: each wave store covers 8
// full 128-B lines) and P2's read becomes one CONTIGUOUS 32-KB chunk/block.
// mid lives in d_ws (R0: the 256-MiB ws fill is timed unconditionally, so
// using ws is free) -- no aliasing anywhere, P2 keeps __restrict__.
// Gate math / LDS phases / bf16 mid byte-identical to R2 -> absmax 0.015625.
//
// Pass 1: bits 0..12 (angles 21..9), x -> packed-bf16 complex mid (d_ws).
// Pass 2: bits 13..21 (angles 8..0), mid -> f32 real parts in d_out.

static __device__ __forceinline__ float bf2f(unsigned short u) {
    return __uint_as_float(((unsigned int)u) << 16);
}
static __device__ __forceinline__ unsigned short f2bf(float f) {
    unsigned int x = __float_as_uint(f);
    x += 0x7FFFu + ((x >> 16) & 1u);          // round-to-nearest-even
    return (unsigned short)(x >> 16);
}
static __device__ __forceinline__ unsigned int packc(float2 v) {
    return (unsigned int)f2bf(v.x) | ((unsigned int)f2bf(v.y) << 16);
}
static __device__ __forceinline__ float2 unpackc(unsigned int u) {
    return make_float2(bf2f((unsigned short)(u & 0xFFFFu)),
                       bf2f((unsigned short)(u >> 16)));
}

static __device__ __forceinline__ void bfly(float2& a, float2& b, float c, float s) {
    float ar = a.x, ai = a.y, br = b.x, bi = b.y;
    a.x = fmaf(c, ar,  s * bi);
    a.y = fmaf(c, ai, -s * br);
    b.x = fmaf(c, br,  s * ai);
    b.y = fmaf(c, bi, -s * ar);
}

// LDS swizzle at float4 granularity (preserves float2-pair adjacency for b128):
// float4 slot f -> f ^ ((f>>3)&7). All b64/b128 phases below are at the
// structural bank floor (enumerated per-round in comments; verified in R2).
static __device__ __forceinline__ unsigned swf(unsigned f) {
    return f ^ ((f >> 3) & 7u);
}
// float2-unit address e -> swizzled float2 address.
static __device__ __forceinline__ unsigned swe(unsigned e) {
    return (swf(e >> 1) << 1) | (e & 1u);
}

// ---------------- Pass 1: global bits 0..12 (angles 21..9) ----------------
// 512 blocks x 512 threads; tile = 8192 contiguous complex (64 KB LDS f32).
// Block p handles hi-block H = ((p&7)<<6)|(p>>3) (XCD-grouped so H and H+1
// share an XCD: their 64-B mid granules combine into full 128-B lines... and
// within one wave t5 already covers granule pairs -> lines complete anyway).
// Phases: A = bits 0..3 (from global, b128 LDS store), barrier, B = bits 4..7
// (b64 LDS rw), barrier, C = bits 11..12 (k pairs) + 8..10 (shfl_xor 1/2/4)
// + bf16 pack + PERMUTED uint4 global store into mid.
__global__ __launch_bounds__(512) void rgate_pass1(
    const float* __restrict__ x, const float* __restrict__ ang,
    unsigned int* __restrict__ mid)
{
    __shared__ __align__(16) float2 tile[8192];
    __shared__ float2 csb[13];                    // csb[j] = (cos,sin)(angle[9+j]/2)
    float4* t4 = (float4*)tile;
    const unsigned t = threadIdx.x;
    if (t < 13) {
        float s, c; sincosf(0.5f * ang[9 + t], &s, &c);
        csb[t] = make_float2(c, s);
    }
    __syncthreads();

    const unsigned p = blockIdx.x;
    const unsigned H = ((p & 7u) << 6) | (p >> 3);     // hi = bits 13..21
    const unsigned base = H << 13;
    float2 v[16];

    // Round A: thread owns 16 CONSECUTIVE elements lo = t*16+k -> 4 float4
    // loads (64 B/lane, wave reads 4 KB contiguous). Gates bits 0..3 = csb[12-j].
    {
        const float4* x4 = (const float4*)(x + base);
        #pragma unroll
        for (int q = 0; q < 4; ++q) {
            const float4 f = x4[(t << 2) + (unsigned)q];
            v[4*q+0] = make_float2(f.x, 0.0f);
            v[4*q+1] = make_float2(f.y, 0.0f);
            v[4*q+2] = make_float2(f.z, 0.0f);
            v[4*q+3] = make_float2(f.w, 0.0f);
        }
    }
    #pragma unroll
    for (int j = 0; j < 4; ++j) {
        const float2 g = csb[12 - j];
        const int m = 1 << j;
        #pragma unroll
        for (int k = 0; k < 16; ++k)
            if (!(k & m)) bfly(v[k], v[k | m], g.x, g.y);
    }
    // b128 stores, slots f = t*8+q; swf spreads q across bank groups (floor).
    #pragma unroll
    for (int q = 0; q < 8; ++q) {
        const unsigned f = (t << 3) + (unsigned)q;
        t4[swf(f)] = make_float4(v[2*q].x, v[2*q].y, v[2*q+1].x, v[2*q+1].y);
    }
    __syncthreads();

    // Round B: lo = l4 + k*16 + hi5*256 (l4 = t&15 -> bits 0..3, k -> 4..7,
    // hi5 = t>>4 in 0..31 -> bits 8..12). Gates bits 4..7 = csb[8-j].
    {
        const unsigned lo = t & 15u, hi = t >> 4;
        #pragma unroll
        for (int k = 0; k < 16; ++k)
            v[k] = tile[swe(lo + ((unsigned)k << 4) + (hi << 8))];
        #pragma unroll
        for (int j = 0; j < 4; ++j) {
            const float2 g = csb[8 - j];
            const int m = 1 << j;
            #pragma unroll
            for (int k = 0; k < 16; ++k)
                if (!(k & m)) bfly(v[k], v[k | m], g.x, g.y);
        }
        #pragma unroll
        for (int k = 0; k < 16; ++k)
            tile[swe(lo + ((unsigned)k << 4) + (hi << 8))] = v[k];
    }
    __syncthreads();

    // Round C: lo = (k&3) | (t>>3)<<2 | (t&7)<<8 | (k>>2)<<11 (bijective:
    // lo{0..1}<-k{0..1}, lo{2..7}<-t{3..8}, lo{8..10}<-t{0..2}=LANE{0..2},
    // lo{11..12}<-k{2..3}). Read 2xb128 per k-group (4 consecutive lo).
    {
        const unsigned cb = ((t >> 3) << 1) | ((t & 7u) << 7);   // f-base
        #pragma unroll
        for (int g = 0; g < 4; ++g) {
            const unsigned f0 = cb | ((unsigned)g << 10);
            const float4 r0 = t4[swf(f0)];
            const float4 r1 = t4[swf(f0 | 1u)];
            v[4*g+0] = make_float2(r0.x, r0.y);
            v[4*g+1] = make_float2(r0.z, r0.w);
            v[4*g+2] = make_float2(r1.x, r1.y);
            v[4*g+3] = make_float2(r1.z, r1.w);
        }
    }
    // Gates bits 11 (csb[1], m=4) and 12 (csb[0], m=8): register pairs.
    {
        const float2 g1 = csb[1];
        #pragma unroll
        for (int k = 0; k < 16; ++k)
            if (!(k & 4)) bfly(v[k], v[k | 4], g1.x, g1.y);
        const float2 g0 = csb[0];
        #pragma unroll
        for (int k = 0; k < 16; ++k)
            if (!(k & 8)) bfly(v[k], v[k | 8], g0.x, g0.y);
    }
    // Gates bits 8,9,10 = csb[4],csb[3],csb[2] via shfl_xor(1/2/4): partner's
    // (re,im) pulled cross-lane; side-symmetric form, no divergence.
    {
        const float2 ga = csb[4];
        #pragma unroll
        for (int k = 0; k < 16; ++k) {
            const float px = __shfl_xor(v[k].x, 1);
            const float py = __shfl_xor(v[k].y, 1);
            v[k] = make_float2(fmaf(ga.x, v[k].x,  ga.y * py),
                               fmaf(ga.x, v[k].y, -ga.y * px));
        }
        const float2 gb = csb[3];
        #pragma unroll
        for (int k = 0; k < 16; ++k) {
            const float px = __shfl_xor(v[k].x, 2);
            const float py = __shfl_xor(v[k].y, 2);
            v[k] = make_float2(fmaf(gb.x, v[k].x,  gb.y * py),
                               fmaf(gb.x, v[k].y, -gb.y * px));
        }
        const float2 gc = csb[2];
        #pragma unroll
        for (int k = 0; k < 16; ++k) {
            const float px = __shfl_xor(v[k].x, 4);
            const float py = __shfl_xor(v[k].y, 4);
            v[k] = make_float2(fmaf(gc.x, v[k].x,  gc.y * py),
                               fmaf(gc.x, v[k].y, -gc.y * px));
        }
    }
    // Pack each 4-element k-group (4 consecutive lo) to one uint4; store to
    // PERMUTED mid: uint index m = (lo>>4)<<13 | H<<4 | (lo&15), i.e. uint4
    // index = ((t>>5) | (t&7)<<4 | g<<7)<<11 | H<<2 | ((t>>3)&3).
    // Per wave per g: 16 distinct 64-B granules at 32-KB stride; t5 spans the
    // two granules of each 128-B line -> 8 FULL lines per wave store.
    {
        uint4* m4 = (uint4*)mid;
        const unsigned ob = (((t >> 5) | ((t & 7u) << 4)) << 11)
                          | (H << 2) | ((t >> 3) & 3u);
        #pragma unroll
        for (int g = 0; g < 4; ++g) {
            uint4 u;
            u.x = packc(v[4*g+0]);
            u.y = packc(v[4*g+1]);
            u.z = packc(v[4*g+2]);
            u.w = packc(v[4*g+3]);
            m4[ob | ((unsigned)g << 18)] = u;      // g<<7 in m-units = <<18... 
        }
    }
}

// ---------------- Pass 2: global bits 13..21 (angles 8..0) ----------------
// 512 blocks x 512 threads. l = bits 0..3, h = bits 13..21 (512 values);
// blk covers bits 4..12. Tile = 8192 complex (64 KB f32), e = h*16 + l at
// swe(e). READ: mid chunk [blk<<13, +8192) uints -- fully CONTIGUOUS 32 KB
// (m = blk<<13 | h<<4 | l). WRITE: out natural order, g = (h<<13)|(blk<<4)|l,
// 64-B granules; XCD-grouped blk so adjacent blocks share 128-B lines.
__global__ __launch_bounds__(512) void rgate_pass2(
    const unsigned int* __restrict__ mid, const float* __restrict__ ang,
    float* __restrict__ outr)
{
    __shared__ __align__(16) float2 tile[8192];
    __shared__ float2 csb[9];                     // csb[j] = (cos,sin)(angle[j]/2)
    float4* t4 = (float4*)tile;
    const unsigned t = threadIdx.x;
    if (t < 9) {
        float s, c; sincosf(0.5f * ang[t], &s, &c);
        csb[t] = make_float2(c, s);
    }
    __syncthreads();

    const unsigned p = blockIdx.x;
    const unsigned blk = ((p & 7u) << 6) | (p >> 3);   // XCD-grouped logical blk
    const uint2* g2 = (const uint2*)mid;               // 1 uint2 = 2 packed complex
    float2 v[16];
    const unsigned tl = t & 7u;                        // l-pair index (l = 2*tl)
    const unsigned th = t >> 3;                        // h bits 3..8

    // Round A: k covers h bits 0..2 (global 13..15, angles 8..6 = csb[8-j]).
    // Read addr (uint2 units) = blk<<12 | h<<3 | tl -- inside the block's own
    // contiguous 32-KB chunk (L2-resident after first touch).
    {
        #pragma unroll
        for (int k = 0; k < 8; ++k) {
            const unsigned h = (th << 3) | (unsigned)k;
            const uint2 u = g2[(blk << 12) | (h << 3) | tl];
            v[2*k]   = unpackc(u.x);
            v[2*k+1] = unpackc(u.y);
        }
        #pragma unroll
        for (int j = 0; j < 3; ++j) {
            const float2 g = csb[8 - j];
            const int m = 2 << j;                      // v-index bits 1..3 = h bits 0..2
            #pragma unroll
            for (int k = 0; k < 16; ++k)
                if (!(k & m)) bfly(v[k], v[k | m], g.x, g.y);
        }
        #pragma unroll
        for (int k = 0; k < 8; ++k) {
            const unsigned h = (th << 3) | (unsigned)k;
            const unsigned f = (h << 3) + tl;          // float4 slot of e=(h<<4)+2*tl
            t4[swf(f)] = make_float4(v[2*k].x, v[2*k].y, v[2*k+1].x, v[2*k+1].y);
        }
    }
    __syncthreads();

    // Round B: k covers h bits 3..6 (global 16..19, angles 5..2 = csb[5-j]).
    // e = (t&127) -> bits 0..6, k -> bits 7..10, (t>>7) -> bits 11..12.
    {
        const unsigned abase = (t & 127u) + ((t >> 7) << 11);
        #pragma unroll
        for (int k = 0; k < 16; ++k)
            v[k] = tile[swe(abase + ((unsigned)k << 7))];
        #pragma unroll
        for (int j = 0; j < 4; ++j) {
            const float2 g = csb[5 - j];
            const int m = 1 << j;
            #pragma unroll
            for (int k = 0; k < 16; ++k)
                if (!(k & m)) bfly(v[k], v[k | m], g.x, g.y);
        }
        #pragma unroll
        for (int k = 0; k < 16; ++k)
            tile[swe(abase + ((unsigned)k << 7))] = v[k];
    }
    __syncthreads();

    // Round C: e = t + k*512. Gates e bits 11..12 (global 20..21, angles 1..0).
    {
        #pragma unroll
        for (int k = 0; k < 16; ++k)
            v[k] = tile[swe(t + ((unsigned)k << 9))];
        {
            const float2 g1 = csb[1];
            #pragma unroll
            for (int k = 0; k < 16; ++k)
                if (!(k & 4)) bfly(v[k], v[k | 4], g1.x, g1.y);
            const float2 g0 = csb[0];
            #pragma unroll
            for (int k = 0; k < 16; ++k)
                if (!(k & 8)) bfly(v[k], v[k | 8], g0.x, g0.y);
        }
        // f32 REAL parts: per wave per k, 4 groups of 16 consecutive floats
        // = 64-B write granules; adjacent blk (same XCD) complete the lines.
        #pragma unroll
        for (int k = 0; k < 16; ++k) {
            const unsigned e = t + ((unsigned)k << 9);
            outr[((e >> 4) << 13) + (blk << 4) + (e & 15u)] = v[k].x;
        }
    }
}

extern "C" void kernel_launch(void* const* d_in, const int* in_sizes, int n_in,
                              void* d_out, int out_size, void* d_ws, size_t ws_size,
                              hipStream_t stream) {
    (void)in_sizes; (void)n_in; (void)out_size; (void)ws_size;
    const float* x   = (const float*)d_in[0];   // float32[2^22]
    const float* ang = (const float*)d_in[1];   // float32[22]
    unsigned int* mid = (unsigned int*)d_ws;    // permuted packed-bf16 mid, 16 MB
    float* outr = (float*)d_out;

    rgate_pass1<<<512, 512, 0, stream>>>(x, ang, mid);
    rgate_pass2<<<512, 512, 0, stream>>>(mid, ang, outr);
}

// Round 8
// 85.092 us; speedup vs baseline: 1.6452x; 1.0792x over previous
//
#include <hip/hip_runtime.h>
#include <hip/hip_cooperative_groups.h>
#include <math.h>

namespace cg = cooperative_groups;

// RGate on 22 qubits: y = (⊗_i exp(-0.5i*angle[i]*sigma_x)) x
//   x:     float32[2^22]  (d_in[0])
//   angle: float32[22]    (d_in[1])
//   out:   float32[2^22]  (d_out) = REAL part of final complex state.
// Site n acts on global bit b = 21-n; gate on bit b uses angle[21-b].
// Butterfly (M = [[c,-is],[-is,c]], symmetric):
//   a' = (c*ar + s*bi, c*ai - s*br);  b' = (c*br + s*ai, c*bi - s*ar)
// Side-symmetric cross-lane form (same formula both sides, p = partner):
//   v' = (c*v.x + s*p.y, c*v.y - s*p.x)
//
// R7: R6's fusion retried with the launch contract fixed. R6 failed because
// __launch_bounds__(512) allows VGPR>128 -> 1 block/CU -> 512-block coop grid
// rejected (hipErrorCooperativeLaunchTooLarge), unchecked -> d_out stayed
// zero (absmax 3.625 = max|ref|). Fix: __launch_bounds__(512,4) caps VGPR at
// 128 (2 blocks/CU -> 512 co-resident), host checks occupancy + return code,
// and falls back to the two verified R1 kernels (shared inlined bodies,
// byte-identical numerics) on any failure. absmax 0.015625 on every path.
//
// Phase 1: bits 0..12 (angles 21..9), x -> packed-bf16 complex mid (in d_out).
// Phase 2: bits 13..21 (angles 8..0), mid -> f32 real parts, in place in d_out.
// d_ws unused (R0: its 256-MiB poison fill is timed unconditionally anyway).

static __device__ __forceinline__ float bf2f(unsigned short u) {
    return __uint_as_float(((unsigned int)u) << 16);
}
static __device__ __forceinline__ unsigned short f2bf(float f) {
    unsigned int x = __float_as_uint(f);
    x += 0x7FFFu + ((x >> 16) & 1u);          // round-to-nearest-even
    return (unsigned short)(x >> 16);
}
static __device__ __forceinline__ unsigned int packc(float2 v) {
    return (unsigned int)f2bf(v.x) | ((unsigned int)f2bf(v.y) << 16);
}
static __device__ __forceinline__ float2 unpackc(unsigned int u) {
    return make_float2(bf2f((unsigned short)(u & 0xFFFFu)),
                       bf2f((unsigned short)(u >> 16)));
}

static __device__ __forceinline__ void bfly(float2& a, float2& b, float c, float s) {
    float ar = a.x, ai = a.y, br = b.x, bi = b.y;
    a.x = fmaf(c, ar,  s * bi);
    a.y = fmaf(c, ai, -s * br);
    b.x = fmaf(c, br,  s * ai);
    b.y = fmaf(c, bi, -s * ar);
}

// LDS swizzle at float4 granularity (preserves float2-pair adjacency for b128):
// float4 slot f -> f ^ ((f>>3)&7). All b64/b128 phases at the structural bank
// floor (enumerated in R1; bodies unchanged).
static __device__ __forceinline__ unsigned swf(unsigned f) {
    return f ^ ((f >> 3) & 7u);
}
static __device__ __forceinline__ unsigned swe(unsigned e) {
    return (swf(e >> 1) << 1) | (e & 1u);
}

// ======================= Phase 1 body (== R1 pass1) =======================
// bits 0..12. tile = 8192 complex (64 KB); bid = tile index (bits 13..21).
static __device__ __forceinline__ void phase1_body(
    const float* __restrict__ x, unsigned int* __restrict__ mid,
    const float2* csbA, float2* tile, unsigned t, unsigned bid)
{
    float4* t4 = (float4*)tile;
    const unsigned base = bid << 13;
    float2 v[16];

    // Round A: thread owns 16 CONSECUTIVE elements e = t*16+k -> 4 float4
    // loads (wave reads 4 KB contiguous). Gates bits 0..3 = csbA[12-j].
    {
        const float4* x4 = (const float4*)(x + base);
        #pragma unroll
        for (int q = 0; q < 4; ++q) {
            const float4 f = x4[(t << 2) + (unsigned)q];
            v[4*q+0] = make_float2(f.x, 0.0f);
            v[4*q+1] = make_float2(f.y, 0.0f);
            v[4*q+2] = make_float2(f.z, 0.0f);
            v[4*q+3] = make_float2(f.w, 0.0f);
        }
    }
    #pragma unroll
    for (int j = 0; j < 4; ++j) {
        const float2 g = csbA[12 - j];
        const int m = 1 << j;
        #pragma unroll
        for (int k = 0; k < 16; ++k)
            if (!(k & m)) bfly(v[k], v[k | m], g.x, g.y);
    }
    #pragma unroll
    for (int q = 0; q < 8; ++q) {
        const unsigned f = (t << 3) + (unsigned)q;
        t4[swf(f)] = make_float4(v[2*q].x, v[2*q].y, v[2*q+1].x, v[2*q+1].y);
    }
    __syncthreads();

    // Round B: e = lo + k*16 + hi*256; gates bits 4..7 = csbA[8-j].
    {
        const unsigned lo = t & 15u, hi = t >> 4;
        #pragma unroll
        for (int k = 0; k < 16; ++k)
            v[k] = tile[swe(lo + ((unsigned)k << 4) + (hi << 8))];
        #pragma unroll
        for (int j = 0; j < 4; ++j) {
            const float2 g = csbA[8 - j];
            const int m = 1 << j;
            #pragma unroll
            for (int k = 0; k < 16; ++k)
                if (!(k & m)) bfly(v[k], v[k | m], g.x, g.y);
        }
        #pragma unroll
        for (int k = 0; k < 16; ++k)
            tile[swe(lo + ((unsigned)k << 4) + (hi << 8))] = v[k];
    }
    __syncthreads();

    // Round C (scrambled): e = (t&7) | ((t>>3)&1)<<12 | (t>>4)<<3 | k<<8.
    // Gates bits 8..11 = csbA[4-j] (k bit j); bit 12 via shfl_xor(8).
    const unsigned cbase = (t & 7u) | (((t >> 3) & 1u) << 12) | ((t >> 4) << 3);
    #pragma unroll
    for (int k = 0; k < 16; ++k)
        v[k] = tile[swe(cbase + ((unsigned)k << 8))];
    #pragma unroll
    for (int j = 0; j < 4; ++j) {
        const float2 g = csbA[4 - j];
        const int m = 1 << j;
        #pragma unroll
        for (int k = 0; k < 16; ++k)
            if (!(k & m)) bfly(v[k], v[k | m], g.x, g.y);
    }
    {
        const float2 gd = csbA[0];
        #pragma unroll
        for (int k = 0; k < 16; ++k) {
            const float px = __shfl_xor(v[k].x, 8);
            const float py = __shfl_xor(v[k].y, 8);
            v[k] = make_float2(fmaf(gd.x, v[k].x,  gd.y * py),
                               fmaf(gd.x, v[k].y, -gd.y * px));
        }
    }
    __syncthreads();   // all round-C reads complete before pack aliases tile

    // Pack to bf16 pairs in LDS (uint region aliased on tile), then coalesced
    // uint4 copy-out. Pack bank = (t&7)|((t>>4&3)<<3), 2-way alias = free.
    {
        unsigned int* up = (unsigned int*)tile;
        #pragma unroll
        for (int k = 0; k < 16; ++k)
            up[cbase + ((unsigned)k << 8)] = packc(v[k]);
    }
    __syncthreads();
    {
        const uint4* tu4 = (const uint4*)tile;
        uint4* m4 = (uint4*)(mid + base);
        #pragma unroll
        for (int i = 0; i < 4; ++i)
            m4[(unsigned)i * 512u + t] = tu4[(unsigned)i * 512u + t];
    }
}

// ======================= Phase 2 body (== R1 pass2) =======================
// bits 13..21, in place in bufu. p = raw blockIdx (XCD-remapped inside).
static __device__ __forceinline__ void phase2_body(
    unsigned int* bufu, const float2* csbB, float2* tile, unsigned t, unsigned p)
{
    float4* t4 = (float4*)tile;
    const unsigned blk = ((p & 7u) << 6) | (p >> 3);   // XCD-grouped logical blk
    const uint2* g2 = (const uint2*)bufu;              // packed complex pairs
    float* outr = (float*)bufu;                        // f32 real view
    float2 v[16];
    const unsigned tl = t & 7u;                        // l-pair index
    const unsigned th = t >> 3;                        // h bits 3..8

    // Round A: k covers h bits 0..2 (global 13..15, angles 8..6 = csbB[8-j]).
    {
        #pragma unroll
        for (int k = 0; k < 8; ++k) {
            const unsigned h = (th << 3) | (unsigned)k;
            const uint2 u = g2[(h << 12) + (blk << 3) + tl];
            v[2*k]   = unpackc(u.x);
            v[2*k+1] = unpackc(u.y);
        }
        #pragma unroll
        for (int j = 0; j < 3; ++j) {
            const float2 g = csbB[8 - j];
            const int m = 2 << j;                      // v bits 1..3 = h bits 0..2
            #pragma unroll
            for (int k = 0; k < 16; ++k)
                if (!(k & m)) bfly(v[k], v[k | m], g.x, g.y);
        }
        #pragma unroll
        for (int k = 0; k < 8; ++k) {
            const unsigned h = (th << 3) | (unsigned)k;
            const unsigned f = (h << 3) + tl;          // float4 slot of e=(h<<4)+2*tl
            t4[swf(f)] = make_float4(v[2*k].x, v[2*k].y, v[2*k+1].x, v[2*k+1].y);
        }
    }
    __syncthreads();   // drains all round-A global reads (in-place safety)

    // Round B: k covers h bits 3..6 (global 16..19, angles 5..2 = csbB[5-j]).
    {
        const unsigned abase = (t & 127u) + ((t >> 7) << 11);
        #pragma unroll
        for (int k = 0; k < 16; ++k)
            v[k] = tile[swe(abase + ((unsigned)k << 7))];
        #pragma unroll
        for (int j = 0; j < 4; ++j) {
            const float2 g = csbB[5 - j];
            const int m = 1 << j;
            #pragma unroll
            for (int k = 0; k < 16; ++k)
                if (!(k & m)) bfly(v[k], v[k | m], g.x, g.y);
        }
        #pragma unroll
        for (int k = 0; k < 16; ++k)
            tile[swe(abase + ((unsigned)k << 7))] = v[k];
    }
    __syncthreads();

    // Round C: e = t + k*512. Gates e bits 11..12 (global 20..21, angles 1..0).
    {
        #pragma unroll
        for (int k = 0; k < 16; ++k)
            v[k] = tile[swe(t + ((unsigned)k << 9))];
        {
            const float2 g1 = csbB[1];
            #pragma unroll
            for (int k = 0; k < 16; ++k)
                if (!(k & 4)) bfly(v[k], v[k | 4], g1.x, g1.y);
            const float2 g0 = csbB[0];
            #pragma unroll
            for (int k = 0; k < 16; ++k)
                if (!(k & 8)) bfly(v[k], v[k | 8], g0.x, g0.y);
        }
        // f32 REAL parts: 64-B write granules, same bytes as round-A reads.
        #pragma unroll
        for (int k = 0; k < 16; ++k) {
            const unsigned e = t + ((unsigned)k << 9);
            outr[((e >> 4) << 13) + (blk << 4) + (e & 15u)] = v[k].x;
        }
    }
}

// ---------------- Fused cooperative kernel (2 blocks/CU enforced) ----------
__global__ __launch_bounds__(512, 4) void rgate_fused(
    const float* __restrict__ x, const float* __restrict__ ang,
    unsigned int* bufu)
{
    __shared__ __align__(16) float2 tile[8192];
    __shared__ float2 csbA[13];    // (cos,sin)(angle[9+j]/2)  (phase 1)
    __shared__ float2 csbB[9];     // (cos,sin)(angle[j]/2)    (phase 2)
    const unsigned t = threadIdx.x;
    if (t < 13) {
        float s, c; sincosf(0.5f * ang[9 + t], &s, &c);
        csbA[t] = make_float2(c, s);
    }
    if (t >= 16 && t < 25) {
        float s, c; sincosf(0.5f * ang[t - 16], &s, &c);
        csbB[t - 16] = make_float2(c, s);
    }
    __syncthreads();

    phase1_body(x, bufu, csbA, tile, t, (unsigned)blockIdx.x);

    __threadfence();            // device-scope release of phase-1 stores
    cg::this_grid().sync();     // also a block-level barrier (tile reuse safe)
    __threadfence();            // device-scope acquire before phase-2 loads

    phase2_body(bufu, csbB, tile, t, (unsigned)blockIdx.x);
}

// ---------------- Fallback: the two verified R1 kernels --------------------
__global__ __launch_bounds__(512) void rgate_pass1k(
    const float* __restrict__ x, const float* __restrict__ ang,
    unsigned int* __restrict__ mid)
{
    __shared__ __align__(16) float2 tile[8192];
    __shared__ float2 csbA[13];
    const unsigned t = threadIdx.x;
    if (t < 13) {
        float s, c; sincosf(0.5f * ang[9 + t], &s, &c);
        csbA[t] = make_float2(c, s);
    }
    __syncthreads();
    phase1_body(x, mid, csbA, tile, t, (unsigned)blockIdx.x);
}

__global__ __launch_bounds__(512) void rgate_pass2k(
    unsigned int* bufu, const float* __restrict__ ang)
{
    __shared__ __align__(16) float2 tile[8192];
    __shared__ float2 csbB[9];
    const unsigned t = threadIdx.x;
    if (t < 9) {
        float s, c; sincosf(0.5f * ang[t], &s, &c);
        csbB[t] = make_float2(c, s);
    }
    __syncthreads();
    phase2_body(bufu, csbB, tile, t, (unsigned)blockIdx.x);
}

extern "C" void kernel_launch(void* const* d_in, const int* in_sizes, int n_in,
                              void* d_out, int out_size, void* d_ws, size_t ws_size,
                              hipStream_t stream) {
    (void)in_sizes; (void)n_in; (void)out_size; (void)d_ws; (void)ws_size;
    const float* x   = (const float*)d_in[0];   // float32[2^22]
    const float* ang = (const float*)d_in[1];   // float32[22]
    unsigned int* bufu = (unsigned int*)d_out;  // mid (bf16 pairs) then f32 out

    // One-time occupancy check (pure query; graph-capture safe). Coop needs
    // 2 blocks/CU x 256 CU >= 512 blocks.
    static int coop_ok = -1;
    if (coop_ok < 0) {
        int nb = 0;
        hipError_t qe = hipOccupancyMaxActiveBlocksPerMultiprocessor(
            &nb, rgate_fused, 512, 0);
        coop_ok = (qe == hipSuccess && nb >= 2) ? 1 : 0;
    }
    if (coop_ok) {
        void* args[] = { (void*)&x, (void*)&ang, (void*)&bufu };
        hipError_t e = hipLaunchCooperativeKernel(
            (const void*)rgate_fused, dim3(512), dim3(512), args, 0, stream);
        if (e == hipSuccess) return;
        coop_ok = 0;   // launch rejected: permanently fall back
    }
    rgate_pass1k<<<512, 512, 0, stream>>>(x, ang, bufu);
    rgate_pass2k<<<512, 512, 0, stream>>>(bufu, ang);
}